// Round 1
// baseline (1478.688 us; speedup 1.0000x reference)
//
#include <hip/hip_runtime.h>
#include <math.h>

// Problem constants
#define N_PTS 16384
#define D_MODEL 256
#define HDIM 128      // H*DH = 4*32
#define KNBR 16
#define NRBF 50
#define NLAYER 4
#define P_OUT 103

// ---------------------------------------------------------------------------
// base[b][j] = b_in[j] + W_in[0][j]*1 + sum_{i=1..255} enc[b][i]*W_in[i][j]
// (x[:,0] is overwritten with 1.0 in the reference, so enc[b][0] is skipped)
__global__ __launch_bounds__(256) void base_kernel(
    const float* __restrict__ enc, const float* __restrict__ W_in,
    const float* __restrict__ b_in, float* __restrict__ base)
{
  int b = blockIdx.x, j = threadIdx.x;
  __shared__ float se[256];
  se[j] = enc[b * 256 + j];
  __syncthreads();
  float acc = b_in[j] + W_in[j];              // W_in row 0 (the x0=1 term)
  for (int i = 1; i < 256; ++i) acc += se[i] * W_in[i * 256 + j];
  base[b * 256 + j] = acc;
}

// h[n][j] = base[batch_idx[n]][j] + pos[n]·W_in[256:259][j]
__global__ __launch_bounds__(256) void embed_kernel(
    const float* __restrict__ base, const int* __restrict__ batch_idx,
    const float* __restrict__ pos, const float* __restrict__ W_in,
    float* __restrict__ h)
{
  int n = blockIdx.x, j = threadIdx.x;
  int b = batch_idx[n];
  float px = pos[n * 3 + 0], py = pos[n * 3 + 1], pz = pos[n * 3 + 2];
  h[(size_t)n * 256 + j] = base[b * 256 + j]
      + px * W_in[256 * 256 + j] + py * W_in[257 * 256 + j] + pz * W_in[258 * 256 + j];
}

// ---------------------------------------------------------------------------
// Generic fp32 tiled GEMM: C[M,P] = A[M,Kd] @ B[Kd,P]  (+ epilogue)
// EPI: 0 none, 1 +bias, 2 +bias+resid, 3 +bias then gelu(tanh approx)
// Requirements: M%64==0, Kd%16==0, Kd row stride float4-aligned. P guarded.
template<int EPI>
__global__ __launch_bounds__(256) void gemm_f32(
    const float* __restrict__ A, const float* __restrict__ B,
    const float* __restrict__ bias, const float* __restrict__ resid,
    float* __restrict__ C, int M, int Kd, int P)
{
  __shared__ float As[16][68];
  __shared__ float Bs[16][68];
  const int tid = threadIdx.x;
  const int m0 = blockIdx.x * 64;
  const int n0 = blockIdx.y * 64;
  const int tx = tid & 15, ty = tid >> 4;
  const int am = tid >> 2, ak = (tid & 3) << 2;   // A: 64 rows x 16 k, float4
  const int bk = tid >> 4, bn = (tid & 15) << 2;  // B: 16 k x 64 n, scalar+guard
  float acc[4][4] = {};
  for (int k0 = 0; k0 < Kd; k0 += 16) {
    float4 av = *reinterpret_cast<const float4*>(A + (size_t)(m0 + am) * Kd + k0 + ak);
    As[ak + 0][am] = av.x; As[ak + 1][am] = av.y;
    As[ak + 2][am] = av.z; As[ak + 3][am] = av.w;
#pragma unroll
    for (int j = 0; j < 4; ++j) {
      int n = n0 + bn + j;
      Bs[bk][bn + j] = (n < P) ? B[(size_t)(k0 + bk) * P + n] : 0.f;
    }
    __syncthreads();
#pragma unroll
    for (int kk = 0; kk < 16; ++kk) {
      float a[4], bb[4];
#pragma unroll
      for (int i = 0; i < 4; ++i) a[i] = As[kk][ty * 4 + i];
#pragma unroll
      for (int j = 0; j < 4; ++j) bb[j] = Bs[kk][tx * 4 + j];
#pragma unroll
      for (int i = 0; i < 4; ++i)
#pragma unroll
        for (int j = 0; j < 4; ++j)
          acc[i][j] += a[i] * bb[j];
    }
    __syncthreads();
  }
#pragma unroll
  for (int i = 0; i < 4; ++i) {
    int m = m0 + ty * 4 + i;
#pragma unroll
    for (int j = 0; j < 4; ++j) {
      int n = n0 + tx * 4 + j;
      if (n < P) {
        float vv = acc[i][j];
        if constexpr (EPI >= 1) vv += bias[n];
        if constexpr (EPI == 2) vv += resid[(size_t)m * P + n];
        if constexpr (EPI == 3) {
          float x = vv;
          float t = tanhf(0.7978845608028654f * (x + 0.044715f * x * x * x));
          vv = 0.5f * x * (1.f + t);
        }
        C[(size_t)m * P + n] = vv;
      }
    }
  }
}

// ---------------------------------------------------------------------------
// Fused per-point attention: rbf + e=rbf@We + kj/vj + logits + softmax + msg
// One block (256 threads) per point.
__global__ __launch_bounds__(256) void attn_kernel(
    const float* __restrict__ q, const float* __restrict__ k,
    const float* __restrict__ v, const float* __restrict__ pos,
    const int* __restrict__ nbrs, const float* __restrict__ mask,
    const float* __restrict__ We_l, float* __restrict__ msg)
{
  __shared__ float sWe[NRBF * 128];   // 25.6 KB
  __shared__ float sRbf[KNBR][NRBF];  // 3.2 KB
  __shared__ float sEV[KNBR * 128];   // e, later vj (8 KB)
  __shared__ float sKj[KNBR * 128];   // 8 KB
  __shared__ float sQ[128];
  __shared__ float sLog[KNBR][4];
  __shared__ float sA[KNBR][4];
  __shared__ float sD[KNBR];
  __shared__ float sMk[KNBR];
  __shared__ int   sNb[KNBR];

  const int n = blockIdx.x;
  const int tid = threadIdx.x;

  for (int i = tid; i < NRBF * 128; i += 256) sWe[i] = We_l[i];
  if (tid < KNBR) {
    int nb = nbrs[n * KNBR + tid];
    sNb[tid] = nb;
    sMk[tid] = mask[n * KNBR + tid];
    float dx = pos[nb * 3 + 0] - pos[n * 3 + 0];
    float dy = pos[nb * 3 + 1] - pos[n * 3 + 1];
    float dz = pos[nb * 3 + 2] - pos[n * 3 + 2];
    sD[tid] = sqrtf(dx * dx + dy * dy + dz * dz + 1e-12f);
  }
  if (tid < 128) sQ[tid] = q[(size_t)n * HDIM + tid];
  __syncthreads();

  const float width = 2.0f / 49.0f;
  const float inv_w = 49.0f / 2.0f;
  for (int i = tid; i < KNBR * NRBF; i += 256) {
    int kk = i / NRBF, r = i - kk * NRBF;
    float t = (sD[kk] - width * (float)r) * inv_w;
    sRbf[kk][r] = expf(-0.5f * t * t);
  }
  __syncthreads();

  // e[k][d] = rbf[k] @ We ; kj[k][d] = k_gather + e
  for (int i = tid; i < KNBR * 128; i += 256) {
    int kk = i >> 7, dd = i & 127;
    float acc = 0.f;
#pragma unroll
    for (int r = 0; r < NRBF; ++r) acc += sRbf[kk][r] * sWe[r * 128 + dd];
    sEV[i] = acc;
    sKj[i] = k[(size_t)sNb[kk] * HDIM + dd] + acc;
  }
  __syncthreads();

  // logits[k][h] = scale * q[h]·kj[k][h], masked
  if (tid < 64) {
    int kk = tid >> 2, hh = tid & 3;
    float acc = 0.f;
    for (int d = 0; d < 32; ++d) acc += sQ[hh * 32 + d] * sKj[kk * 128 + hh * 32 + d];
    acc *= 0.17677669529663687f;  // 1/sqrt(32)
    sLog[kk][hh] = (sMk[kk] > 0.f) ? acc : -1e9f;
  }
  __syncthreads();

  // softmax over k, per head (tiny: 4 threads)
  if (tid < 4) {
    int hh = tid;
    float mx = -3.4e38f;
    for (int kk = 0; kk < KNBR; ++kk) mx = fmaxf(mx, sLog[kk][hh]);
    float s = 0.f;
    for (int kk = 0; kk < KNBR; ++kk) {
      float e = expf(sLog[kk][hh] - mx);
      sA[kk][hh] = e; s += e;
    }
    float inv = 1.f / s;
    for (int kk = 0; kk < KNBR; ++kk) sA[kk][hh] *= inv * sMk[kk];
  }
  __syncthreads();

  // vj = e + v_gather (overwrite sEV)
  for (int i = tid; i < KNBR * 128; i += 256) {
    int kk = i >> 7, dd = i & 127;
    sEV[i] += v[(size_t)sNb[kk] * HDIM + dd];
  }
  __syncthreads();

  if (tid < 128) {
    int hh = tid >> 5;
    float acc = 0.f;
#pragma unroll
    for (int kk = 0; kk < KNBR; ++kk) acc += sA[kk][hh] * sEV[kk * 128 + tid];
    msg[(size_t)n * HDIM + tid] = acc;
  }
}

// ---------------------------------------------------------------------------
// In-place LayerNorm over last dim (256), one block per row
__global__ __launch_bounds__(256) void ln_kernel(
    float* __restrict__ h, const float* __restrict__ g, const float* __restrict__ b)
{
  int n = blockIdx.x, j = threadIdx.x;
  float x = h[(size_t)n * 256 + j];
  float s = x, ss = x * x;
#pragma unroll
  for (int off = 32; off > 0; off >>= 1) {
    s += __shfl_down(s, off, 64);
    ss += __shfl_down(ss, off, 64);
  }
  __shared__ float rs[4], rss[4];
  int wid = j >> 6, lane = j & 63;
  if (lane == 0) { rs[wid] = s; rss[wid] = ss; }
  __syncthreads();
  s = rs[0] + rs[1] + rs[2] + rs[3];
  ss = rss[0] + rss[1] + rss[2] + rss[3];
  float mu = s * (1.f / 256.f);
  float var = ss * (1.f / 256.f) - mu * mu;
  float inv = 1.0f / sqrtf(var + 1e-5f);
  h[(size_t)n * 256 + j] = g[j] * (x - mu) * inv + b[j];
}

// ---------------------------------------------------------------------------
extern "C" void kernel_launch(void* const* d_in, const int* in_sizes, int n_in,
                              void* d_out, int out_size, void* d_ws, size_t ws_size,
                              hipStream_t stream) {
  const float* enc    = (const float*)d_in[0];
  const float* pos    = (const float*)d_in[1];
  const int*   bidx   = (const int*)  d_in[2];
  const int*   nbrs   = (const int*)  d_in[3];
  const float* mask   = (const float*)d_in[4];
  const float* W_in   = (const float*)d_in[5];
  const float* b_in   = (const float*)d_in[6];
  const float* Wq     = (const float*)d_in[7];
  const float* Wk     = (const float*)d_in[8];
  const float* Wv     = (const float*)d_in[9];
  const float* We     = (const float*)d_in[10];
  const float* Wo     = (const float*)d_in[11];
  const float* bo     = (const float*)d_in[12];
  const float* Wfc    = (const float*)d_in[13];
  const float* bfc    = (const float*)d_in[14];
  const float* ln_g   = (const float*)d_in[15];
  const float* ln_b   = (const float*)d_in[16];
  const float* W_out  = (const float*)d_in[17];
  const float* b_out  = (const float*)d_in[18];
  float* out = (float*)d_out;

  const int N = N_PTS, D = D_MODEL, HD = HDIM;
  float* ws = (float*)d_ws;
  float* h    = ws;                       // N*D
  float* h2   = h   + (size_t)N * D;      // N*D
  float* qb   = h2  + (size_t)N * D;      // N*HD
  float* kb   = qb  + (size_t)N * HD;
  float* vb   = kb  + (size_t)N * HD;
  float* msg  = vb  + (size_t)N * HD;
  float* base = msg + (size_t)N * HD;     // B*D = 32768

  base_kernel<<<128, 256, 0, stream>>>(enc, W_in, b_in, base);
  embed_kernel<<<N, 256, 0, stream>>>(base, bidx, pos, W_in, h);

  for (int l = 0; l < NLAYER; ++l) {
    const float* Wq_l  = Wq  + (size_t)l * D * HD;
    const float* Wk_l  = Wk  + (size_t)l * D * HD;
    const float* Wv_l  = Wv  + (size_t)l * D * HD;
    const float* We_l  = We  + (size_t)l * NRBF * HD;
    const float* Wo_l  = Wo  + (size_t)l * HD * D;
    const float* bo_l  = bo  + (size_t)l * D;
    const float* Wfc_l = Wfc + (size_t)l * D * D;
    const float* bfc_l = bfc + (size_t)l * D;
    const float* lg_l  = ln_g + (size_t)l * D;
    const float* lb_l  = ln_b + (size_t)l * D;

    gemm_f32<0><<<dim3(N / 64, HD / 64), 256, 0, stream>>>(h, Wq_l, nullptr, nullptr, qb, N, D, HD);
    gemm_f32<0><<<dim3(N / 64, HD / 64), 256, 0, stream>>>(h, Wk_l, nullptr, nullptr, kb, N, D, HD);
    gemm_f32<0><<<dim3(N / 64, HD / 64), 256, 0, stream>>>(h, Wv_l, nullptr, nullptr, vb, N, D, HD);

    attn_kernel<<<N, 256, 0, stream>>>(qb, kb, vb, pos, nbrs, mask, We_l, msg);

    // h2 = h + msg @ Wo + bo
    gemm_f32<2><<<dim3(N / 64, D / 64), 256, 0, stream>>>(msg, Wo_l, bo_l, h, h2, N, HD, D);
    ln_kernel<<<N, 256, 0, stream>>>(h2, lg_l, lb_l);
    // h = gelu(h2 @ Wfc + bfc)
    gemm_f32<3><<<dim3(N / 64, D / 64), 256, 0, stream>>>(h2, Wfc_l, bfc_l, nullptr, h, N, D, D);
  }

  gemm_f32<1><<<dim3(N / 64, (P_OUT + 63) / 64), 256, 0, stream>>>(h, W_out, b_out, nullptr, out, N, D, P_OUT);
}

// Round 2
// 519.314 us; speedup vs baseline: 2.8474x; 2.8474x over previous
//
#include <hip/hip_runtime.h>
#include <hip/hip_bf16.h>
#include <math.h>

#define N_PTS 16384
#define NLAYER 4

typedef __attribute__((ext_vector_type(8))) short bfrag;
typedef __attribute__((ext_vector_type(4))) float f32x4;
typedef unsigned short ushort_t;
typedef unsigned int uint_t;

__device__ __forceinline__ ushort_t f2b(float f) {
  __hip_bfloat16 h = __float2bfloat16(f);
  return *reinterpret_cast<const ushort_t*>(&h);
}
__device__ __forceinline__ float b2f(ushort_t u) {
  union { uint_t i; float f; } c; c.i = ((uint_t)u) << 16; return c.f;
}
__device__ __forceinline__ float blo(uint_t u) {
  union { uint_t i; float f; } c; c.i = u << 16; return c.f;
}
__device__ __forceinline__ float bhi(uint_t u) {
  union { uint_t i; float f; } c; c.i = u & 0xffff0000u; return c.f;
}

// ---------------------------------------------------------------------------
// base[b][j] = b_in[j] + W_in[0][j] + sum_{i=1..255} enc[b][i]*W_in[i][j]
__global__ __launch_bounds__(256) void base_kernel(
    const float* __restrict__ enc, const float* __restrict__ W_in,
    const float* __restrict__ b_in, float* __restrict__ base)
{
  int b = blockIdx.x, j = threadIdx.x;
  __shared__ float se[256];
  se[j] = enc[b * 256 + j];
  __syncthreads();
  float acc = b_in[j] + W_in[j];
  for (int i = 1; i < 256; ++i) acc += se[i] * W_in[i * 256 + j];
  base[b * 256 + j] = acc;
}

// h[n][j] fp32 + bf16
__global__ __launch_bounds__(256) void embed_kernel(
    const float* __restrict__ base, const int* __restrict__ batch_idx,
    const float* __restrict__ pos, const float* __restrict__ W_in,
    float* __restrict__ h, ushort_t* __restrict__ h_bf)
{
  int n = blockIdx.x, j = threadIdx.x;
  int b = batch_idx[n];
  float px = pos[n * 3 + 0], py = pos[n * 3 + 1], pz = pos[n * 3 + 2];
  float v = base[b * 256 + j]
      + px * W_in[256 * 256 + j] + py * W_in[257 * 256 + j] + pz * W_in[258 * 256 + j];
  h[(size_t)n * 256 + j] = v;
  h_bf[(size_t)n * 256 + j] = f2b(v);
}

// ---------------------------------------------------------------------------
// Weight prep: transposed bf16 layouts (BT is P x K row-major)
// WqextT[l][j][k], j<128: Wq[l][k][j]; j>=128: sum_d Wq[l][k][h*32+d]*We[l][r][h*32+d]
__global__ __launch_bounds__(256) void prep_qext(
    const float* __restrict__ Wq, const float* __restrict__ We, ushort_t* __restrict__ out)
{
  int idx = blockIdx.x * 256 + threadIdx.x;  // < 4*328*256
  int l = idx / (328 * 256);
  int rem = idx - l * (328 * 256);
  int j = rem >> 8, k = rem & 255;
  float v;
  if (j < 128) v = Wq[((size_t)l * 256 + k) * 128 + j];
  else {
    int p = j - 128, hq = p / 50, r = p - hq * 50;
    const float* wq = &Wq[((size_t)l * 256 + k) * 128 + hq * 32];
    const float* we = &We[((size_t)l * 50 + r) * 128 + hq * 32];
    v = 0.f;
#pragma unroll
    for (int d = 0; d < 32; ++d) v += wq[d] * we[d];
  }
  out[idx] = f2b(v);
}

// WkvT[l][j][k]: j<128 -> Wk[l][k][j]; else Wv[l][k][j-128]
__global__ __launch_bounds__(256) void prep_kv(
    const float* __restrict__ Wk, const float* __restrict__ Wv, ushort_t* __restrict__ out)
{
  int idx = blockIdx.x * 256 + threadIdx.x;  // < 4*256*256
  int l = idx >> 16, rem = idx & 65535;
  int j = rem >> 8, k = rem & 255;
  float v = (j < 128) ? Wk[((size_t)l * 256 + k) * 128 + j]
                      : Wv[((size_t)l * 256 + k) * 128 + (j - 128)];
  out[idx] = f2b(v);
}

// BcatT[l][j][k2]: k2<128: Wo[l][k2][j]; k2<328: sum_d We[l][r][h*32+d]*Wo[l][h*32+d][j]; else 0
__global__ __launch_bounds__(256) void prep_bcat(
    const float* __restrict__ We, const float* __restrict__ Wo, ushort_t* __restrict__ out)
{
  int idx = blockIdx.x * 256 + threadIdx.x;  // < 4*256*352
  if (idx >= 4 * 256 * 352) return;
  int l = idx / (256 * 352);
  int rem = idx - l * (256 * 352);
  int j = rem / 352, k2 = rem - j * 352;
  float v = 0.f;
  if (k2 < 128) v = Wo[((size_t)l * 128 + k2) * 256 + j];
  else if (k2 < 328) {
    int p = k2 - 128, hq = p / 50, r = p - hq * 50;
    const float* we = &We[((size_t)l * 50 + r) * 128 + hq * 32];
    const float* wo = &Wo[((size_t)l * 128 + hq * 32) * 256 + j];
#pragma unroll
    for (int d = 0; d < 32; ++d) v += we[d] * wo[(size_t)d * 256];
  }
  out[idx] = f2b(v);
}

__global__ __launch_bounds__(256) void prep_wfc(
    const float* __restrict__ Wfc, ushort_t* __restrict__ out)
{
  int idx = blockIdx.x * 256 + threadIdx.x;  // < 4*256*256
  int l = idx >> 16, rem = idx & 65535;
  int j = rem >> 8, k = rem & 255;
  out[idx] = f2b(Wfc[((size_t)l * 256 + k) * 256 + j]);
}

__global__ __launch_bounds__(256) void prep_wout(
    const float* __restrict__ W_out, ushort_t* __restrict__ out)
{
  int idx = blockIdx.x * 256 + threadIdx.x;  // < 103*256
  if (idx >= 103 * 256) return;
  int j = idx >> 8, k = idx & 255;
  out[idx] = f2b(W_out[(size_t)k * 103 + j]);
}

// ---------------------------------------------------------------------------
// bf16 MFMA GEMM: C[M,P] = A[M,K] @ BT[P,K]^T, 128x128 tile, BK=32, 4 waves.
// EPI: 0 none, 1 +bias, 2 +bias+resid, 3 +bias+gelu. WF: write fp32, WB: write bf16.
template<int EPI, bool WF, bool WB>
__global__ __launch_bounds__(256) void gemm_bf16(
    const ushort_t* __restrict__ A, const ushort_t* __restrict__ BT,
    const float* __restrict__ bias, const float* __restrict__ resid,
    float* __restrict__ Cf, ushort_t* __restrict__ Cb,
    int M, int K, int P)
{
  __shared__ __align__(16) short As[128 * 40];
  __shared__ __align__(16) short Bs[128 * 40];
  const int tid = threadIdx.x;
  const int m0 = blockIdx.x * 128, n0 = blockIdx.y * 128;
  const int lane = tid & 63, wv = tid >> 6;
  const int wm = wv >> 1, wn = wv & 1;
  const int l15 = lane & 15, l4 = lane >> 4;
  const int sr = tid >> 1, sc = tid & 1;

  f32x4 acc[4][4];
#pragma unroll
  for (int i = 0; i < 4; ++i)
#pragma unroll
    for (int j = 0; j < 4; ++j) acc[i][j] = (f32x4){0.f, 0.f, 0.f, 0.f};

  const ushort_t* gA = A + (size_t)(m0 + sr) * K + sc * 16;
  const int bnrow = n0 + sr;
  const ushort_t* gB = BT + (size_t)bnrow * K + sc * 16;
  const bool bvalid = (bnrow < P);
  short* wAs = As + sr * 40 + sc * 16;
  short* wBs = Bs + sr * 40 + sc * 16;
  const bfrag zf = {0, 0, 0, 0, 0, 0, 0, 0};

  for (int k0 = 0; k0 < K; k0 += 32) {
    *(bfrag*)wAs       = *(const bfrag*)(gA + k0);
    *(bfrag*)(wAs + 8) = *(const bfrag*)(gA + k0 + 8);
    if (bvalid) {
      *(bfrag*)wBs       = *(const bfrag*)(gB + k0);
      *(bfrag*)(wBs + 8) = *(const bfrag*)(gB + k0 + 8);
    } else {
      *(bfrag*)wBs = zf;
      *(bfrag*)(wBs + 8) = zf;
    }
    __syncthreads();
    bfrag af[4], bf[4];
#pragma unroll
    for (int m = 0; m < 4; ++m)
      af[m] = *(const bfrag*)(As + (wm * 64 + m * 16 + l15) * 40 + l4 * 8);
#pragma unroll
    for (int nn = 0; nn < 4; ++nn)
      bf[nn] = *(const bfrag*)(Bs + (wn * 64 + nn * 16 + l15) * 40 + l4 * 8);
#pragma unroll
    for (int m = 0; m < 4; ++m)
#pragma unroll
      for (int nn = 0; nn < 4; ++nn)
        acc[m][nn] = __builtin_amdgcn_mfma_f32_16x16x32_bf16(af[m], bf[nn], acc[m][nn], 0, 0, 0);
    __syncthreads();
  }

#pragma unroll
  for (int m = 0; m < 4; ++m) {
    const int rbase = m0 + wm * 64 + m * 16 + l4 * 4;
#pragma unroll
    for (int nn = 0; nn < 4; ++nn) {
      const int c = n0 + wn * 64 + nn * 16 + l15;
      if (c < P) {
#pragma unroll
        for (int i = 0; i < 4; ++i) {
          const int r = rbase + i;
          float v = acc[m][nn][i];
          if (EPI >= 1) v += bias[c];
          if (EPI == 2) v += resid[(size_t)r * P + c];
          if (EPI == 3) {
            float x = v;
            float t = tanhf(0.7978845608028654f * (x + 0.044715f * x * x * x));
            v = 0.5f * x * (1.f + t);
          }
          if (WF) Cf[(size_t)r * P + c] = v;
          if (WB) Cb[(size_t)r * P + c] = f2b(v);
        }
      }
    }
  }
}

// ---------------------------------------------------------------------------
// Fused attention, wave-per-point. Reads qext (fp32 N x 328: [q | qWe]),
// kvb (bf16 N x 256: [k | v]). Writes Amsg (bf16 N x 352: [msgv | arbf | 0pad]).
__global__ __launch_bounds__(256) void attn_kernel(
    const float* __restrict__ qext, const ushort_t* __restrict__ kvb,
    const float* __restrict__ pos, const int* __restrict__ nbrs,
    const float* __restrict__ mask, ushort_t* __restrict__ Amsg)
{
  __shared__ float sRbf[4][16][52];
  __shared__ float sQ[4][128];
  __shared__ float sQE[4][200];
  __shared__ float sA[4][64];
  __shared__ float sD[4][16];
  __shared__ float sMk[4][16];
  __shared__ int   sNb[4][16];

  const int tid = threadIdx.x;
  const int lane = tid & 63, w = tid >> 6;
  const int kk = lane >> 2, hh = lane & 3;

  for (int it = 0; it < 2; ++it) {
    const int n = blockIdx.x * 8 + w * 2 + it;
    if (lane < 16) {
      int nb = nbrs[n * 16 + lane];
      sNb[w][lane] = nb;
      sMk[w][lane] = mask[n * 16 + lane];
      float dx = pos[nb * 3 + 0] - pos[n * 3 + 0];
      float dy = pos[nb * 3 + 1] - pos[n * 3 + 1];
      float dz = pos[nb * 3 + 2] - pos[n * 3 + 2];
      sD[w][lane] = sqrtf(dx * dx + dy * dy + dz * dz + 1e-12f);
    }
    {
      float2 qv = *(const float2*)&qext[(size_t)n * 328 + lane * 2];
      sQ[w][lane * 2] = qv.x; sQ[w][lane * 2 + 1] = qv.y;
    }
    for (int i = lane; i < 200; i += 64) sQE[w][i] = qext[(size_t)n * 328 + 128 + i];
    __syncthreads();

    const float wstep = 2.f / 49.f, invw = 24.5f;
    for (int k2 = 0; k2 < 16; ++k2) {
      if (lane < 50) {
        float t = (sD[w][k2] - wstep * (float)lane) * invw;
        sRbf[w][k2][lane] = expf(-0.5f * t * t);
      }
    }
    __syncthreads();

    // logits: lane (kk, hh)
    int nb = sNb[w][kk];
    const uint_t* krow = (const uint_t*)(kvb + (size_t)nb * 256 + hh * 32);
    float qk = 0.f;
#pragma unroll
    for (int c8 = 0; c8 < 4; ++c8) {
      uint4 kv4 = *(const uint4*)(krow + c8 * 4);
      float4 q0 = *(const float4*)&sQ[w][hh * 32 + c8 * 8];
      float4 q1 = *(const float4*)&sQ[w][hh * 32 + c8 * 8 + 4];
      qk += q0.x * blo(kv4.x) + q0.y * bhi(kv4.x)
          + q0.z * blo(kv4.y) + q0.w * bhi(kv4.y)
          + q1.x * blo(kv4.z) + q1.y * bhi(kv4.z)
          + q1.z * blo(kv4.w) + q1.w * bhi(kv4.w);
    }
    float qe = 0.f;
#pragma unroll
    for (int r = 0; r < 50; ++r) qe += sRbf[w][kk][r] * sQE[w][hh * 50 + r];
    float lg = 0.17677669529663687f * (qk + qe);
    lg = (sMk[w][kk] > 0.f) ? lg : -1e9f;

    float mx = lg;
#pragma unroll
    for (int off = 4; off < 64; off <<= 1) mx = fmaxf(mx, __shfl_xor(mx, off, 64));
    float ex = expf(lg - mx);
    float sm = ex;
#pragma unroll
    for (int off = 4; off < 64; off <<= 1) sm += __shfl_xor(sm, off, 64);
    sA[w][kk * 4 + hh] = ex / sm * sMk[w][kk];
    __syncthreads();

    // arbf -> Amsg[128 + h*50 + r]
#pragma unroll
    for (int h2 = 0; h2 < 4; ++h2) {
      if (lane < 50) {
        float a2 = 0.f;
#pragma unroll
        for (int k2 = 0; k2 < 16; ++k2) a2 += sA[w][k2 * 4 + h2] * sRbf[w][k2][lane];
        Amsg[(size_t)n * 352 + 128 + h2 * 50 + lane] = f2b(a2);
      }
    }
    // msgv -> Amsg[0..127]
#pragma unroll
    for (int half = 0; half < 2; ++half) {
      int df = lane + half * 64;
      int h2 = df >> 5;
      float a2 = 0.f;
#pragma unroll
      for (int k2 = 0; k2 < 16; ++k2)
        a2 += sA[w][k2 * 4 + h2] * b2f(kvb[(size_t)sNb[w][k2] * 256 + 128 + df]);
      Amsg[(size_t)n * 352 + df] = f2b(a2);
    }
    if (lane < 24) Amsg[(size_t)n * 352 + 328 + lane] = 0;  // bf16 zero pad
    __syncthreads();
  }
}

// ---------------------------------------------------------------------------
// LayerNorm row (256), reads fp32, writes bf16
__global__ __launch_bounds__(256) void ln_bf(
    const float* __restrict__ h, const float* __restrict__ g,
    const float* __restrict__ b, ushort_t* __restrict__ out)
{
  int n = blockIdx.x, j = threadIdx.x;
  float x = h[(size_t)n * 256 + j];
  float s = x, ss = x * x;
#pragma unroll
  for (int off = 32; off > 0; off >>= 1) {
    s += __shfl_down(s, off, 64);
    ss += __shfl_down(ss, off, 64);
  }
  __shared__ float rs[4], rss[4];
  int wid = j >> 6, lane = j & 63;
  if (lane == 0) { rs[wid] = s; rss[wid] = ss; }
  __syncthreads();
  s = rs[0] + rs[1] + rs[2] + rs[3];
  ss = rss[0] + rss[1] + rss[2] + rss[3];
  float mu = s * (1.f / 256.f);
  float var = ss * (1.f / 256.f) - mu * mu;
  float inv = 1.0f / sqrtf(var + 1e-5f);
  out[(size_t)n * 256 + j] = f2b(g[j] * (x - mu) * inv + b[j]);
}

// ---------------------------------------------------------------------------
extern "C" void kernel_launch(void* const* d_in, const int* in_sizes, int n_in,
                              void* d_out, int out_size, void* d_ws, size_t ws_size,
                              hipStream_t stream) {
  const float* enc    = (const float*)d_in[0];
  const float* pos    = (const float*)d_in[1];
  const int*   bidx   = (const int*)  d_in[2];
  const int*   nbrs   = (const int*)  d_in[3];
  const float* mask   = (const float*)d_in[4];
  const float* W_in   = (const float*)d_in[5];
  const float* b_in   = (const float*)d_in[6];
  const float* Wq     = (const float*)d_in[7];
  const float* Wk     = (const float*)d_in[8];
  const float* Wv     = (const float*)d_in[9];
  const float* We     = (const float*)d_in[10];
  const float* Wo     = (const float*)d_in[11];
  const float* bo     = (const float*)d_in[12];
  const float* Wfc    = (const float*)d_in[13];
  const float* bfc    = (const float*)d_in[14];
  const float* ln_g   = (const float*)d_in[15];
  const float* ln_b   = (const float*)d_in[16];
  const float* W_out  = (const float*)d_in[17];
  const float* b_out  = (const float*)d_in[18];
  float* out = (float*)d_out;

  const int N = N_PTS;
  float* ws = (float*)d_ws;
  float*    h     = ws;                               // N*256 fp32
  float*    qext  = h + (size_t)N * 256;              // N*328 fp32
  ushort_t* kvb   = (ushort_t*)(qext + (size_t)N * 328); // N*256 bf16
  ushort_t* hln   = kvb;                              // alias (disjoint lifetime)
  ushort_t* h_bf  = kvb + (size_t)N * 256;            // N*256 bf16
  ushort_t* Amsg  = h_bf + (size_t)N * 256;           // N*352 bf16
  float*    base  = (float*)(Amsg + (size_t)N * 352); // 128*256 fp32
  ushort_t* WqT   = (ushort_t*)(base + 128 * 256);    // 4*328*256
  ushort_t* WkvT  = WqT  + 4 * 328 * 256;             // 4*256*256
  ushort_t* BcT   = WkvT + 4 * 256 * 256;             // 4*256*352
  ushort_t* WfT   = BcT  + 4 * 256 * 352;             // 4*256*256
  ushort_t* WoT   = WfT  + 4 * 256 * 256;             // 103*256

  base_kernel<<<128, 256, 0, stream>>>(enc, W_in, b_in, base);
  embed_kernel<<<N, 256, 0, stream>>>(base, bidx, pos, W_in, h, h_bf);
  prep_qext<<<(4 * 328 * 256) / 256, 256, 0, stream>>>(Wq, We, WqT);
  prep_kv<<<(4 * 256 * 256) / 256, 256, 0, stream>>>(Wk, Wv, WkvT);
  prep_bcat<<<(4 * 256 * 352 + 255) / 256, 256, 0, stream>>>(We, Wo, BcT);
  prep_wfc<<<(4 * 256 * 256) / 256, 256, 0, stream>>>(Wfc, WfT);
  prep_wout<<<(103 * 256 + 255) / 256, 256, 0, stream>>>(W_out, WoT);

  for (int l = 0; l < NLAYER; ++l) {
    const ushort_t* WqT_l  = WqT  + (size_t)l * 328 * 256;
    const ushort_t* WkvT_l = WkvT + (size_t)l * 256 * 256;
    const ushort_t* BcT_l  = BcT  + (size_t)l * 256 * 352;
    const ushort_t* WfT_l  = WfT  + (size_t)l * 256 * 256;
    const float* bo_l  = bo  + (size_t)l * 256;
    const float* bfc_l = bfc + (size_t)l * 256;
    const float* lg_l  = ln_g + (size_t)l * 256;
    const float* lb_l  = ln_b + (size_t)l * 256;

    // qext = h_bf @ [Wq | Wq_e]  (fp32 out)
    gemm_bf16<0, true, false><<<dim3(N / 128, 3), 256, 0, stream>>>(
        h_bf, WqT_l, nullptr, nullptr, qext, nullptr, N, 256, 328);
    // kvb = h_bf @ [Wk | Wv]  (bf16 out)
    gemm_bf16<0, false, true><<<dim3(N / 128, 2), 256, 0, stream>>>(
        h_bf, WkvT_l, nullptr, nullptr, nullptr, kvb, N, 256, 256);

    attn_kernel<<<N / 8, 256, 0, stream>>>(qext, kvb, pos, nbrs, mask, Amsg);

    // h = h + [msgv | arbf] @ [Wo ; WeWo] + bo  (in-place resid, fp32)
    gemm_bf16<2, true, false><<<dim3(N / 128, 2), 256, 0, stream>>>(
        Amsg, BcT_l, bo_l, h, h, nullptr, N, 352, 256);

    ln_bf<<<N, 256, 0, stream>>>(h, lg_l, lb_l, hln);

    // h = gelu(hln @ Wfc + bfc)  (fp32 + bf16)
    gemm_bf16<3, true, true><<<dim3(N / 128, 2), 256, 0, stream>>>(
        hln, WfT_l, bfc_l, nullptr, h, h_bf, N, 256, 256);
  }

  gemm_bf16<1, true, false><<<dim3(N / 128, 1), 256, 0, stream>>>(
      h_bf, WoT, b_out, nullptr, out, nullptr, N, 256, 103);
}

// Round 3
// 401.183 us; speedup vs baseline: 3.6858x; 1.2945x over previous
//
#include <hip/hip_runtime.h>
#include <hip/hip_bf16.h>
#include <math.h>

#define N_PTS 16384
#define NLAYER 4

typedef __attribute__((ext_vector_type(8))) short bfrag;
typedef __attribute__((ext_vector_type(4))) float f32x4;
typedef __attribute__((ext_vector_type(4))) unsigned short u16x4;
typedef unsigned short ushort_t;
typedef unsigned int uint_t;

__device__ __forceinline__ ushort_t f2b(float f) {
  __hip_bfloat16 h = __float2bfloat16(f);
  return *reinterpret_cast<const ushort_t*>(&h);
}
__device__ __forceinline__ float b2f(ushort_t u) {
  union { uint_t i; float f; } c; c.i = ((uint_t)u) << 16; return c.f;
}
__device__ __forceinline__ float blo(uint_t u) {
  union { uint_t i; float f; } c; c.i = u << 16; return c.f;
}
__device__ __forceinline__ float bhi(uint_t u) {
  union { uint_t i; float f; } c; c.i = u & 0xffff0000u; return c.f;
}

// ---------------------------------------------------------------------------
__global__ __launch_bounds__(256) void base_kernel(
    const float* __restrict__ enc, const float* __restrict__ W_in,
    const float* __restrict__ b_in, float* __restrict__ base)
{
  int b = blockIdx.x, j = threadIdx.x;
  __shared__ float se[256];
  se[j] = enc[b * 256 + j];
  __syncthreads();
  float acc = b_in[j] + W_in[j];
  for (int i = 1; i < 256; ++i) acc += se[i] * W_in[i * 256 + j];
  base[b * 256 + j] = acc;
}

__global__ __launch_bounds__(256) void embed_kernel(
    const float* __restrict__ base, const int* __restrict__ batch_idx,
    const float* __restrict__ pos, const float* __restrict__ W_in,
    float* __restrict__ h, ushort_t* __restrict__ h_bf)
{
  int n = blockIdx.x, j = threadIdx.x;
  int b = batch_idx[n];
  float px = pos[n * 3 + 0], py = pos[n * 3 + 1], pz = pos[n * 3 + 2];
  float v = base[b * 256 + j]
      + px * W_in[256 * 256 + j] + py * W_in[257 * 256 + j] + pz * W_in[258 * 256 + j];
  h[(size_t)n * 256 + j] = v;
  h_bf[(size_t)n * 256 + j] = f2b(v);
}

// ---------------------------------------------------------------------------
// Merged QKV weight, transposed+padded: [l][j][k], j in [0,640):
//   j<128: Wq col j; 128<=j<328: (Wq @ We^T head-block) col; 328<=j<456: Wk;
//   456<=j<584: Wv; else 0.
__global__ __launch_bounds__(256) void prep_qkv(
    const float* __restrict__ Wq, const float* __restrict__ Wk,
    const float* __restrict__ Wv, const float* __restrict__ We,
    ushort_t* __restrict__ out)
{
  int idx = blockIdx.x * 256 + threadIdx.x;  // < 4*640*256
  int l = idx / (640 * 256);
  int rem = idx - l * (640 * 256);
  int j = rem >> 8, k = rem & 255;
  float v = 0.f;
  if (j < 128) v = Wq[((size_t)l * 256 + k) * 128 + j];
  else if (j < 328) {
    int p = j - 128, hq = p / 50, r = p - hq * 50;
    const float* wq = &Wq[((size_t)l * 256 + k) * 128 + hq * 32];
    const float* we = &We[((size_t)l * 50 + r) * 128 + hq * 32];
#pragma unroll
    for (int d = 0; d < 32; ++d) v += wq[d] * we[d];
  } else if (j < 456) v = Wk[((size_t)l * 256 + k) * 128 + (j - 328)];
  else if (j < 584) v = Wv[((size_t)l * 256 + k) * 128 + (j - 456)];
  out[idx] = f2b(v);
}

// BcatT[l][j][k2] (256 x 352): k2<128: Wo[k2][j]; k2<328: (We@Wo)[..]; else 0
__global__ __launch_bounds__(256) void prep_bcat(
    const float* __restrict__ We, const float* __restrict__ Wo, ushort_t* __restrict__ out)
{
  int idx = blockIdx.x * 256 + threadIdx.x;  // < 4*256*352
  if (idx >= 4 * 256 * 352) return;
  int l = idx / (256 * 352);
  int rem = idx - l * (256 * 352);
  int j = rem / 352, k2 = rem - j * 352;
  float v = 0.f;
  if (k2 < 128) v = Wo[((size_t)l * 128 + k2) * 256 + j];
  else if (k2 < 328) {
    int p = k2 - 128, hq = p / 50, r = p - hq * 50;
    const float* we = &We[((size_t)l * 50 + r) * 128 + hq * 32];
    const float* wo = &Wo[((size_t)l * 128 + hq * 32) * 256 + j];
#pragma unroll
    for (int d = 0; d < 32; ++d) v += we[d] * wo[(size_t)d * 256];
  }
  out[idx] = f2b(v);
}

__global__ __launch_bounds__(256) void prep_wfc(
    const float* __restrict__ Wfc, ushort_t* __restrict__ out)
{
  int idx = blockIdx.x * 256 + threadIdx.x;  // < 4*256*256
  int l = idx >> 16, rem = idx & 65535;
  int j = rem >> 8, k = rem & 255;
  out[idx] = f2b(Wfc[((size_t)l * 256 + k) * 256 + j]);
}

// padded to 128 rows
__global__ __launch_bounds__(256) void prep_wout(
    const float* __restrict__ W_out, ushort_t* __restrict__ out)
{
  int idx = blockIdx.x * 256 + threadIdx.x;  // < 128*256
  int j = idx >> 8, k = idx & 255;
  out[idx] = (j < 103) ? f2b(W_out[(size_t)k * 103 + j]) : (ushort_t)0;
}

// ---------------------------------------------------------------------------
// bf16 MFMA GEMM, 128x64 tile, 4 waves (2x2), wave-tile 64x32, BK=32.
// EPI 0: split-write qext_b(328)/kvb(256) bf16, valid c<584
// EPI 1: +bias, fp32 out ld=103, guard c<103
// EPI 2: +bias+resid fp32 (ld 256), in-place h update
// EPI 3: +bias+gelu, fp32 (ld 256) + bf16 (ld 256)
template<int EPI>
__global__ __launch_bounds__(256) void gemm_bf16(
    const ushort_t* __restrict__ A, const ushort_t* __restrict__ BT,
    const float* __restrict__ bias, const float* __restrict__ resid,
    float* __restrict__ Cf, ushort_t* __restrict__ Cb, ushort_t* __restrict__ Cb2,
    int K)
{
  __shared__ __align__(16) short As[128 * 40];
  __shared__ __align__(16) short Bs[64 * 40];
  const int tid = threadIdx.x;
  const int m0 = blockIdx.x * 128, n0 = blockIdx.y * 64;
  const int lane = tid & 63, wv = tid >> 6;
  const int wm = wv >> 1, wn = wv & 1;
  const int l15 = lane & 15, l4 = lane >> 4;
  const int asr = tid >> 1, asc = tid & 1;
  const int bsr = tid >> 2, bsc = tid & 3;

  f32x4 acc[4][2];
#pragma unroll
  for (int i = 0; i < 4; ++i)
#pragma unroll
    for (int j = 0; j < 2; ++j) acc[i][j] = (f32x4){0.f, 0.f, 0.f, 0.f};

  const ushort_t* gA = A + (size_t)(m0 + asr) * K + asc * 16;
  const ushort_t* gB = BT + (size_t)(n0 + bsr) * K + bsc * 8;
  short* wAs = As + asr * 40 + asc * 16;
  short* wBs = Bs + bsr * 40 + bsc * 8;

  for (int k0 = 0; k0 < K; k0 += 32) {
    *(bfrag*)wAs       = *(const bfrag*)(gA + k0);
    *(bfrag*)(wAs + 8) = *(const bfrag*)(gA + k0 + 8);
    *(bfrag*)wBs       = *(const bfrag*)(gB + k0);
    __syncthreads();
    bfrag af[4], bf[2];
#pragma unroll
    for (int m = 0; m < 4; ++m)
      af[m] = *(const bfrag*)(As + (wm * 64 + m * 16 + l15) * 40 + l4 * 8);
#pragma unroll
    for (int nn = 0; nn < 2; ++nn)
      bf[nn] = *(const bfrag*)(Bs + (wn * 32 + nn * 16 + l15) * 40 + l4 * 8);
#pragma unroll
    for (int m = 0; m < 4; ++m)
#pragma unroll
      for (int nn = 0; nn < 2; ++nn)
        acc[m][nn] = __builtin_amdgcn_mfma_f32_16x16x32_bf16(af[m], bf[nn], acc[m][nn], 0, 0, 0);
    __syncthreads();
  }

#pragma unroll
  for (int m = 0; m < 4; ++m) {
    const int rbase = m0 + wm * 64 + m * 16 + l4 * 4;
#pragma unroll
    for (int nn = 0; nn < 2; ++nn) {
      const int c = n0 + wn * 32 + nn * 16 + l15;
#pragma unroll
      for (int i = 0; i < 4; ++i) {
        const int r = rbase + i;
        float v = acc[m][nn][i];
        if (EPI == 0) {
          if (c < 328) Cb[(size_t)r * 328 + c] = f2b(v);
          else if (c < 584) Cb2[(size_t)r * 256 + (c - 328)] = f2b(v);
        } else if (EPI == 1) {
          if (c < 103) Cf[(size_t)r * 103 + c] = v + bias[c];
        } else if (EPI == 2) {
          Cf[(size_t)r * 256 + c] = v + bias[c] + resid[(size_t)r * 256 + c];
        } else {
          float x = v + bias[c];
          float t = tanhf(0.7978845608028654f * (x + 0.044715f * x * x * x));
          float gl = 0.5f * x * (1.f + t);
          Cf[(size_t)r * 256 + c] = gl;
          Cb[(size_t)r * 256 + c] = f2b(gl);
        }
      }
    }
  }
}

// ---------------------------------------------------------------------------
// Group-local attention. 256 blocks x 512 threads. Block = half group (64 pts),
// stages full group's K/V (128x256 bf16, stride 264) in LDS. Wave per point,
// 8 points per wave, no in-loop block barriers (all scratch per-wave).
__global__ __launch_bounds__(512) void attn_kernel(
    const ushort_t* __restrict__ qext, const ushort_t* __restrict__ kvb,
    const float* __restrict__ pos, const int* __restrict__ nbrs,
    const float* __restrict__ mask, ushort_t* __restrict__ Amsg)
{
  __shared__ ushort_t sKV[128 * 264];   // 67.6 KB
  __shared__ float sPos[128 * 3];
  __shared__ ushort_t sQ[8][336];
  __shared__ float sRbf[8][16][52];
  __shared__ float sA[8][64];
  __shared__ float sD[8][16];
  __shared__ float sMk[8][16];
  __shared__ int   sRn[8][16];

  const int tid = threadIdx.x;
  const int lane = tid & 63, w = tid >> 6;
  const int g = blockIdx.x >> 1, half = blockIdx.x & 1;
  const int base_pt = g * 128;

  for (int e = tid; e < 128 * 32; e += 512) {
    int r = e >> 5, c8 = e & 31;
    uint4 v = *(const uint4*)(kvb + ((size_t)(base_pt + r)) * 256 + c8 * 8);
    *(uint4*)(&sKV[r * 264 + c8 * 8]) = v;
  }
  for (int e = tid; e < 384; e += 512) sPos[e] = pos[(size_t)base_pt * 3 + e];
  __syncthreads();

  const int kk = lane >> 2, hh = lane & 3;
  for (int it = 0; it < 8; ++it) {
    const int rl = half * 64 + w * 8 + it;
    const int n = base_pt + rl;
    if (lane < 16) {
      int nb = nbrs[n * 16 + lane];
      int rn = nb - base_pt;
      sRn[w][lane] = rn;
      sMk[w][lane] = mask[n * 16 + lane];
      float dx = sPos[rn * 3 + 0] - sPos[rl * 3 + 0];
      float dy = sPos[rn * 3 + 1] - sPos[rl * 3 + 1];
      float dz = sPos[rn * 3 + 2] - sPos[rl * 3 + 2];
      sD[w][lane] = sqrtf(dx * dx + dy * dy + dz * dz + 1e-12f);
    }
    if (lane < 41)
      *(uint4*)(&sQ[w][lane * 8]) = *(const uint4*)(qext + (size_t)n * 328 + lane * 8);
    // rbf: lane -> (kk2 = lane&15, r = (lane>>4) + 4j)
    {
      int kk2 = lane & 15;
      float dk = sD[w][kk2];
      int r0 = lane >> 4;
#pragma unroll
      for (int j = 0; j < 13; ++j) {
        int r = r0 + j * 4;
        if (r < 50) {
          float t = (dk - (2.f / 49.f) * (float)r) * 24.5f;
          sRbf[w][kk2][r] = expf(-0.5f * t * t);
        }
      }
    }
    // logits: lane = (kk, hh)
    int rn = sRn[w][kk];
    const ushort_t* krow = &sKV[rn * 264 + hh * 32];
    float qk = 0.f;
#pragma unroll
    for (int c8 = 0; c8 < 4; ++c8) {
      uint4 kv4 = *(const uint4*)(krow + c8 * 8);
      const uint_t* q4 = (const uint_t*)(&sQ[w][hh * 32 + c8 * 8]);
      uint_t qa = q4[0], qb = q4[1], qc = q4[2], qd = q4[3];
      qk += blo(qa) * blo(kv4.x) + bhi(qa) * bhi(kv4.x)
          + blo(qb) * blo(kv4.y) + bhi(qb) * bhi(kv4.y)
          + blo(qc) * blo(kv4.z) + bhi(qc) * bhi(kv4.z)
          + blo(qd) * blo(kv4.w) + bhi(qd) * bhi(kv4.w);
    }
    float qe = 0.f;
#pragma unroll
    for (int r = 0; r < 50; ++r) qe += sRbf[w][kk][r] * b2f(sQ[w][128 + hh * 50 + r]);
    float lg = 0.17677669529663687f * (qk + qe);
    lg = (sMk[w][kk] > 0.f) ? lg : -1e9f;

    float mx = lg;
#pragma unroll
    for (int off = 4; off < 64; off <<= 1) mx = fmaxf(mx, __shfl_xor(mx, off, 64));
    float ex = expf(lg - mx);
    float sm = ex;
#pragma unroll
    for (int off = 4; off < 64; off <<= 1) sm += __shfl_xor(sm, off, 64);
    sA[w][kk * 4 + hh] = ex / sm * sMk[w][kk];

    // arbf
#pragma unroll
    for (int h2 = 0; h2 < 4; ++h2) {
      if (lane < 50) {
        float a2 = 0.f;
#pragma unroll
        for (int k2 = 0; k2 < 16; ++k2) a2 += sA[w][k2 * 4 + h2] * sRbf[w][k2][lane];
        Amsg[(size_t)n * 352 + 128 + h2 * 50 + lane] = f2b(a2);
      }
    }
    // msgv
#pragma unroll
    for (int hf = 0; hf < 2; ++hf) {
      int df = lane + hf * 64;
      int h2 = df >> 5;
      float a2 = 0.f;
#pragma unroll
      for (int k2 = 0; k2 < 16; ++k2)
        a2 += sA[w][k2 * 4 + h2] * b2f(sKV[sRn[w][k2] * 264 + 128 + df]);
      Amsg[(size_t)n * 352 + df] = f2b(a2);
    }
    if (lane < 24) Amsg[(size_t)n * 352 + 328 + lane] = 0;
  }
}

// ---------------------------------------------------------------------------
// LayerNorm: wave per row, 4 rows/block, float4, no LDS.
__global__ __launch_bounds__(256) void ln_bf(
    const float* __restrict__ h, const float* __restrict__ g,
    const float* __restrict__ b, ushort_t* __restrict__ out)
{
  int row = blockIdx.x * 4 + (threadIdx.x >> 6);
  int lane = threadIdx.x & 63;
  float4 x = *(const float4*)(h + (size_t)row * 256 + lane * 4);
  float s = x.x + x.y + x.z + x.w;
  float ss = x.x * x.x + x.y * x.y + x.z * x.z + x.w * x.w;
#pragma unroll
  for (int off = 1; off < 64; off <<= 1) {
    s += __shfl_xor(s, off, 64);
    ss += __shfl_xor(ss, off, 64);
  }
  float mu = s * (1.f / 256.f);
  float var = ss * (1.f / 256.f) - mu * mu;
  float inv = 1.0f / sqrtf(var + 1e-5f);
  float4 gg = *(const float4*)(g + lane * 4);
  float4 bb = *(const float4*)(b + lane * 4);
  u16x4 o;
  o.x = f2b(gg.x * (x.x - mu) * inv + bb.x);
  o.y = f2b(gg.y * (x.y - mu) * inv + bb.y);
  o.z = f2b(gg.z * (x.z - mu) * inv + bb.z);
  o.w = f2b(gg.w * (x.w - mu) * inv + bb.w);
  *(u16x4*)(out + (size_t)row * 256 + lane * 4) = o;
}

// ---------------------------------------------------------------------------
extern "C" void kernel_launch(void* const* d_in, const int* in_sizes, int n_in,
                              void* d_out, int out_size, void* d_ws, size_t ws_size,
                              hipStream_t stream) {
  const float* enc    = (const float*)d_in[0];
  const float* pos    = (const float*)d_in[1];
  const int*   bidx   = (const int*)  d_in[2];
  const int*   nbrs   = (const int*)  d_in[3];
  const float* mask   = (const float*)d_in[4];
  const float* W_in   = (const float*)d_in[5];
  const float* b_in   = (const float*)d_in[6];
  const float* Wq     = (const float*)d_in[7];
  const float* Wk     = (const float*)d_in[8];
  const float* Wv     = (const float*)d_in[9];
  const float* We     = (const float*)d_in[10];
  const float* Wo     = (const float*)d_in[11];
  const float* bo     = (const float*)d_in[12];
  const float* Wfc    = (const float*)d_in[13];
  const float* bfc    = (const float*)d_in[14];
  const float* ln_g   = (const float*)d_in[15];
  const float* ln_b   = (const float*)d_in[16];
  const float* W_out  = (const float*)d_in[17];
  const float* b_out  = (const float*)d_in[18];
  float* out = (float*)d_out;

  const int N = N_PTS;
  float* ws = (float*)d_ws;
  float*    h      = ws;                                  // N*256 fp32
  ushort_t* qext_b = (ushort_t*)(h + (size_t)N * 256);    // N*328 bf16
  ushort_t* kvb    = qext_b + (size_t)N * 328;            // N*256 bf16
  ushort_t* hln    = kvb;                                 // alias, disjoint lifetime
  ushort_t* h_bf   = kvb + (size_t)N * 256;               // N*256 bf16
  ushort_t* Amsg   = h_bf + (size_t)N * 256;              // N*352 bf16
  float*    base   = (float*)(Amsg + (size_t)N * 352);    // 128*256 fp32
  ushort_t* WqkvT  = (ushort_t*)(base + 128 * 256);       // 4*640*256
  ushort_t* BcT    = WqkvT + 4 * 640 * 256;               // 4*256*352
  ushort_t* WfT    = BcT  + 4 * 256 * 352;                // 4*256*256
  ushort_t* WoT    = WfT  + 4 * 256 * 256;                // 128*256

  base_kernel<<<128, 256, 0, stream>>>(enc, W_in, b_in, base);
  embed_kernel<<<N, 256, 0, stream>>>(base, bidx, pos, W_in, h, h_bf);
  prep_qkv<<<(4 * 640 * 256) / 256, 256, 0, stream>>>(Wq, Wk, Wv, We, WqkvT);
  prep_bcat<<<(4 * 256 * 352 + 255) / 256, 256, 0, stream>>>(We, Wo, BcT);
  prep_wfc<<<(4 * 256 * 256) / 256, 256, 0, stream>>>(Wfc, WfT);
  prep_wout<<<(128 * 256) / 256, 256, 0, stream>>>(W_out, WoT);

  for (int l = 0; l < NLAYER; ++l) {
    const ushort_t* WqkvT_l = WqkvT + (size_t)l * 640 * 256;
    const ushort_t* BcT_l   = BcT   + (size_t)l * 256 * 352;
    const ushort_t* WfT_l   = WfT   + (size_t)l * 256 * 256;
    const float* bo_l  = bo  + (size_t)l * 256;
    const float* bfc_l = bfc + (size_t)l * 256;
    const float* lg_l  = ln_g + (size_t)l * 256;
    const float* lb_l  = ln_b + (size_t)l * 256;

    // [qext | k | v] = h_bf @ Wqkv  (split bf16 writes)
    gemm_bf16<0><<<dim3(N / 128, 10), 256, 0, stream>>>(
        h_bf, WqkvT_l, nullptr, nullptr, nullptr, qext_b, kvb, 256);

    attn_kernel<<<256, 512, 0, stream>>>(qext_b, kvb, pos, nbrs, mask, Amsg);

    // h = h + [msgv | arbf] @ [Wo ; WeWo] + bo
    gemm_bf16<2><<<dim3(N / 128, 4), 256, 0, stream>>>(
        Amsg, BcT_l, bo_l, h, h, nullptr, nullptr, 352);

    ln_bf<<<N / 4, 256, 0, stream>>>(h, lg_l, lb_l, hln);

    // h = gelu(hln @ Wfc + bfc), also bf16 copy
    gemm_bf16<3><<<dim3(N / 128, 4), 256, 0, stream>>>(
        hln, WfT_l, bfc_l, nullptr, h, h_bf, nullptr, 256);
  }

  gemm_bf16<1><<<dim3(N / 128, 2), 256, 0, stream>>>(
      h_bf, WoT, b_out, nullptr, out, nullptr, nullptr, 256);
}